// Round 22
// baseline (112.288 us; speedup 1.0000x reference)
//
#include <hip/hip_runtime.h>
#include <hip/hip_bf16.h>
#include <hip/hip_fp8.h>

#define BB 4096
#define DD 256
#define CC 5994
#define CPAD 6144
#define PARTS 64
#define NCH 6             // 16-col chunks per part (96 cols/part)
#define COSM 0.9800665778412416f   // cos(0.2)
#define SINM 0.19866933079506122f  // sin(0.2)

typedef __attribute__((ext_vector_type(4))) float f32x4;

__device__ __forceinline__ unsigned char f2fp8(float f) {
  return __hip_fp8_e4m3(f).__x;   // OCP e4m3fn, saturating
}

// ---- kernel 1 (fused prep): blocks 0..1023 xnorm, 1024..1407 wnorm ----
// swizzled fp8 layout (elements == bytes):
//   off = chunk*4096 + ks*512 + lg*128 + lr*8 + h
//   (row|col) = chunk*16 + lr, k = ks*32 + lg*8 + h
__global__ void k_prep(const float* __restrict__ x, const float* __restrict__ W,
                       unsigned char* __restrict__ xnS, unsigned char* __restrict__ wnS,
                       unsigned* __restrict__ accum) {
  int b = blockIdx.x;
  int t = threadIdx.x;
  if (b < 1024) {
    int tgi = t >> 6, l = t & 63;
    int row = b * 4 + tgi;
    float4 v = reinterpret_cast<const float4*>(x + (size_t)row * DD)[l];
    float ss = v.x * v.x + v.y * v.y + v.z * v.z + v.w * v.w;
#pragma unroll
    for (int m = 32; m >= 1; m >>= 1) ss += __shfl_xor(ss, m, 64);
    float inv = 1.0f / fmaxf(sqrtf(ss), 1e-12f);
    unsigned wd = (unsigned)f2fp8(v.x * inv) |
                  ((unsigned)f2fp8(v.y * inv) << 8) |
                  ((unsigned)f2fp8(v.z * inv) << 16) |
                  ((unsigned)f2fp8(v.w * inv) << 24);
    int off = (row >> 4) * 4096 + (l >> 3) * 512 + ((l >> 1) & 3) * 128 + (row & 15) * 8 + (l & 1) * 4;
    *reinterpret_cast<unsigned*>(xnS + off) = wd;
  } else {
    if (b == 1024 && t < 4) accum[t] = 0u;  // loss, corr, ticket, spare
    __shared__ float pp[16][17];
    __shared__ float sinv[16];
    int lr = t & 15, u = t >> 4;
    int bb = b - 1024;
    int chunk = (bb & 7) * 48 + (bb >> 3);  // XCD-locality remap (bijective on [0,384))
    int c = chunk * 16 + lr;
    int D0 = u * 16;
    float v[16];
    float ss = 0.f;
#pragma unroll
    for (int i = 0; i < 16; ++i) {
      float xv = (c < CC) ? W[(size_t)(D0 + i) * CC + c] : 0.f;
      v[i] = xv; ss += xv * xv;
    }
    pp[u][lr] = ss;
    __syncthreads();
    if (t < 16) {
      float tot = 0.f;
#pragma unroll
      for (int g = 0; g < 16; ++g) tot += pp[g][t];
      sinv[t] = (chunk * 16 + t < CC) ? 1.0f / fmaxf(sqrtf(tot), 1e-12f) : 0.f;
    }
    __syncthreads();
    float inv = sinv[lr];
    int base = chunk * 4096 + (u >> 1) * 512 + ((2 * u) & 3) * 128 + lr * 8;
    unsigned long long w0 = 0ull, w1 = 0ull;
#pragma unroll
    for (int i = 0; i < 8; ++i)
      w0 |= ((unsigned long long)f2fp8(v[i] * inv)) << (8 * i);
#pragma unroll
    for (int i = 0; i < 8; ++i)
      w1 |= ((unsigned long long)f2fp8(v[8 + i] * inv)) << (8 * i);
    *reinterpret_cast<unsigned long long*>(wnS + base) = w0;
    *reinterpret_cast<unsigned long long*>(wnS + base + 128) = w1;
  }
}

// ---- kernel 2: fused fp8 MFMA GEMM + softmax stats (r18 body) ----
// Occupancy lever: grid 2048 (8 blocks/CU supply) + VGPR cap 85 (6 waves/SIMD
// demand) -- fp8 fragment registers are half the bf16 kernel's 116, so ~84 fits.
__launch_bounds__(256, 6)
__global__ void k_main(const unsigned char* __restrict__ xnS,
                       const unsigned char* __restrict__ wnS,
                       const int* __restrict__ label,
                       float* __restrict__ sp, float* __restrict__ vmp,
                       float* __restrict__ vtp) {
  int bid = blockIdx.x;
  int sw = (bid & 7) * 256 + (bid >> 3);  // XCD-contiguous remap (2048 = 8*256)
  int part = sw >> 5;                     // 0..63: column part (96 cols)
  int rowblk = sw & 31;                   // 0..31: 128-row block
  int t = threadIdx.x, w = t >> 6, l = t & 63;
  int lg = l >> 4, lr = l & 15;
  int r0 = rowblk * 128 + w * 32;         // this wave's first row (M=32)

  // A fragments (swizzled fp8, contiguous per wave): 8 bytes per (rt, ks)
  long a[2][8];
#pragma unroll
  for (int rt = 0; rt < 2; ++rt) {
    const unsigned char* ap = xnS + ((r0 >> 4) + rt) * 4096 + lg * 128 + lr * 8;
#pragma unroll
    for (int ks = 0; ks < 8; ++ks)
      a[rt][ks] = *reinterpret_cast<const long*>(ap + ks * 512);
  }
  int lab[8];
#pragma unroll
  for (int rt = 0; rt < 2; ++rt)
#pragma unroll
    for (int j = 0; j < 4; ++j) lab[rt * 4 + j] = label[r0 + rt * 16 + lg * 4 + j];

  float s[8], vm[8], vt[8];
#pragma unroll
  for (int i = 0; i < 8; ++i) { s[i] = 0.f; vm[i] = -2.f; vt[i] = -2.f; }

  // B fragments: chunk c of this part at wnS[part*24576 + c*4096 + ks*512 + l*8]
  const unsigned char* bbase = wnS + (size_t)part * 24576 + l * 8;
  long b[8];
#pragma unroll
  for (int ks = 0; ks < 8; ++ks)
    b[ks] = *reinterpret_cast<const long*>(bbase + ks * 512);

#pragma unroll 2
  for (int c = 0; c < NCH; ++c) {
    long bn[8];
    if (c + 1 < NCH) {  // issue next chunk's loads; hide under MFMA+epilogue
      const unsigned char* bp = bbase + (c + 1) * 4096;
#pragma unroll
      for (int ks = 0; ks < 8; ++ks)
        bn[ks] = *reinterpret_cast<const long*>(bp + ks * 512);
    }
    f32x4 acc0 = {0.f, 0.f, 0.f, 0.f}, acc1 = {0.f, 0.f, 0.f, 0.f};
#pragma unroll
    for (int ks = 0; ks < 8; ++ks) {
      acc0 = __builtin_amdgcn_mfma_f32_16x16x32_fp8_fp8(a[0][ks], b[ks], acc0, 0, 0, 0);
      acc1 = __builtin_amdgcn_mfma_f32_16x16x32_fp8_fp8(a[1][ks], b[ks], acc1, 0, 0, 0);
    }
    int col = part * 96 + c * 16 + lr;
#pragma unroll
    for (int j = 0; j < 4; ++j) {
      float v0 = acc0[j], v1 = acc1[j];
      s[j]     += __expf(__builtin_fmaf(v0, 30.f, -30.f));  // fixed max 30
      s[4 + j] += __expf(__builtin_fmaf(v1, 30.f, -30.f));
      bool i0 = (col == lab[j]), i1 = (col == lab[4 + j]);
      vt[j]     = i0 ? v0 : vt[j];
      vt[4 + j] = i1 ? v1 : vt[4 + j];
      vm[j]     = fmaxf(vm[j],     i0 ? -2.f : v0);
      vm[4 + j] = fmaxf(vm[4 + j], i1 ? -2.f : v1);
    }
#pragma unroll
    for (int ks = 0; ks < 8; ++ks) b[ks] = bn[ks];  // renamed away by unroll
  }

  // reduce across the 16 lanes sharing each output row
#pragma unroll
  for (int i = 0; i < 8; ++i) {
#pragma unroll
    for (int mk = 1; mk < 16; mk <<= 1) {
      s[i] += __shfl_xor(s[i], mk, 64);
      vm[i] = fmaxf(vm[i], __shfl_xor(vm[i], mk, 64));
      vt[i] = fmaxf(vt[i], __shfl_xor(vt[i], mk, 64));
    }
    if (lr == 0) {
      int row = r0 + (i >> 2) * 16 + lg * 4 + (i & 3);
      int idx = row * PARTS + part;      // [row][part] (r11-verified layout)
      sp[idx] = s[i]; vmp[idx] = vm[i]; vtp[idx] = vt[i];
    }
  }
}

// ---- kernel 3 (tail v3, r18-proven): 64 blocks x 64 threads, float4 reads ----
__global__ void k_tail(const float* __restrict__ sp, const float* __restrict__ vmp,
                       const float* __restrict__ vtp, float* __restrict__ accum,
                       float* __restrict__ out) {
  int t = threadIdx.x;            // 64
  int row = blockIdx.x * 64 + t;  // grid 64
  float s = 0.f, vm = -2.f, vt = -2.f;
#pragma unroll
  for (int q = 0; q < PARTS / 4; ++q) {
    float4 aq = reinterpret_cast<const float4*>(sp + row * PARTS)[q];
    float4 mq = reinterpret_cast<const float4*>(vmp + row * PARTS)[q];
    float4 tq = reinterpret_cast<const float4*>(vtp + row * PARTS)[q];
    s += aq.x + aq.y + aq.z + aq.w;
    vm = fmaxf(vm, fmaxf(fmaxf(mq.x, mq.y), fmaxf(mq.z, mq.w)));
    vt = fmaxf(vt, fmaxf(fmaxf(tq.x, tq.y), fmaxf(tq.z, tq.w)));
  }
  float vtc = fminf(fmaxf(vt, -1.f + 1e-7f), 1.f + 1e-7f);
  float sn = sqrtf(fmaxf(1.f - vtc * vtc, 0.f));
  float tg = 30.f * (vtc * COSM - sn * SINM);
  float sadj = s - __expf(30.f * vt - 30.f) + __expf(tg - 30.f);
  float loss = 30.f + logf(sadj) - tg;
  float corr = (tg >= 30.f * vm) ? 1.f : 0.f;
#pragma unroll
  for (int mk = 32; mk >= 1; mk >>= 1) {
    loss += __shfl_xor(loss, mk, 64);
    corr += __shfl_xor(corr, mk, 64);
  }
  if (t == 0) {
    atomicAdd(accum + 0, loss);
    atomicAdd(accum + 1, corr);
    __threadfence();
    unsigned ticket = atomicAdd(reinterpret_cast<unsigned*>(accum) + 2, 1u);
    if (ticket == 63) {  // last block: read via atomic (device-coherent point)
      float L = atomicAdd(accum + 0, 0.0f);
      float Cr = atomicAdd(accum + 1, 0.0f);
      out[0] = L / (float)BB;
      out[1] = Cr * (100.0f / (float)BB);
    }
  }
}

extern "C" void kernel_launch(void* const* d_in, const int* in_sizes, int n_in,
                              void* d_out, int out_size, void* d_ws, size_t ws_size,
                              hipStream_t stream) {
  const float* x = (const float*)d_in[0];
  const float* W = (const float*)d_in[1];
  const int* label = (const int*)d_in[2];
  float* out = (float*)d_out;

  char* ws = (char*)d_ws;
  unsigned char* wnS = (unsigned char*)(ws);                 // 6144*256 = 1,572,864
  unsigned char* xnS = (unsigned char*)(ws + 1572864);       // 4096*256 = 1,048,576
  size_t po = 2621440;
  float* sp  = (float*)(ws + po);                            // 4096*64*4 = 1,048,576
  float* vmp = (float*)(ws + po + 1048576);
  float* vtp = (float*)(ws + po + 2097152);
  float* accum = (float*)(ws + po + 3145728);                // [loss, corr, ticket, pad]

  k_prep<<<1408, 256, 0, stream>>>(x, W, xnS, wnS, (unsigned*)accum);
  k_main<<<2048, 256, 0, stream>>>(xnS, wnS, label, sp, vmp, vtp);
  k_tail<<<BB / 64, 64, 0, stream>>>(sp, vmp, vtp, accum, out);
}

// Round 23
// 39.404 us; speedup vs baseline: 2.8497x; 2.8497x over previous
//
#include <hip/hip_runtime.h>
#include <hip/hip_bf16.h>
#include <hip/hip_fp8.h>

#define BB 4096
#define DD 256
#define CC 5994
#define CPAD 6144
#define PARTS 64
#define NCH 6             // 16-col chunks per part (96 cols/part)
#define COSM 0.9800665778412416f   // cos(0.2)
#define SINM 0.19866933079506122f  // sin(0.2)

typedef __attribute__((ext_vector_type(4))) float f32x4;

__device__ __forceinline__ unsigned char f2fp8(float f) {
  return __hip_fp8_e4m3(f).__x;   // OCP e4m3fn, saturating
}

// ---- kernel 1 (fused prep): blocks 0..1023 xnorm, 1024..1407 wnorm ----
// swizzled fp8 layout (elements == bytes):
//   off = chunk*4096 + ks*512 + lg*128 + lr*8 + h
//   (row|col) = chunk*16 + lr, k = ks*32 + lg*8 + h
__global__ void k_prep(const float* __restrict__ x, const float* __restrict__ W,
                       unsigned char* __restrict__ xnS, unsigned char* __restrict__ wnS,
                       unsigned* __restrict__ accum) {
  int b = blockIdx.x;
  int t = threadIdx.x;
  if (b < 1024) {
    int tgi = t >> 6, l = t & 63;
    int row = b * 4 + tgi;
    float4 v = reinterpret_cast<const float4*>(x + (size_t)row * DD)[l];
    float ss = v.x * v.x + v.y * v.y + v.z * v.z + v.w * v.w;
#pragma unroll
    for (int m = 32; m >= 1; m >>= 1) ss += __shfl_xor(ss, m, 64);
    float inv = 1.0f / fmaxf(sqrtf(ss), 1e-12f);
    unsigned wd = (unsigned)f2fp8(v.x * inv) |
                  ((unsigned)f2fp8(v.y * inv) << 8) |
                  ((unsigned)f2fp8(v.z * inv) << 16) |
                  ((unsigned)f2fp8(v.w * inv) << 24);
    int off = (row >> 4) * 4096 + (l >> 3) * 512 + ((l >> 1) & 3) * 128 + (row & 15) * 8 + (l & 1) * 4;
    *reinterpret_cast<unsigned*>(xnS + off) = wd;
  } else {
    if (b == 1024 && t < 4) accum[t] = 0u;  // loss, corr, ticket, spare
    __shared__ float pp[16][17];
    __shared__ float sinv[16];
    int lr = t & 15, u = t >> 4;
    int bb = b - 1024;
    int chunk = (bb & 7) * 48 + (bb >> 3);  // XCD-locality remap (bijective on [0,384))
    int c = chunk * 16 + lr;
    int D0 = u * 16;
    float v[16];
    float ss = 0.f;
#pragma unroll
    for (int i = 0; i < 16; ++i) {
      float xv = (c < CC) ? W[(size_t)(D0 + i) * CC + c] : 0.f;
      v[i] = xv; ss += xv * xv;
    }
    pp[u][lr] = ss;
    __syncthreads();
    if (t < 16) {
      float tot = 0.f;
#pragma unroll
      for (int g = 0; g < 16; ++g) tot += pp[g][t];
      sinv[t] = (chunk * 16 + t < CC) ? 1.0f / fmaxf(sqrtf(tot), 1e-12f) : 0.f;
    }
    __syncthreads();
    float inv = sinv[lr];
    int base = chunk * 4096 + (u >> 1) * 512 + ((2 * u) & 3) * 128 + lr * 8;
    unsigned long long w0 = 0ull, w1 = 0ull;
#pragma unroll
    for (int i = 0; i < 8; ++i)
      w0 |= ((unsigned long long)f2fp8(v[i] * inv)) << (8 * i);
#pragma unroll
    for (int i = 0; i < 8; ++i)
      w1 |= ((unsigned long long)f2fp8(v[8 + i] * inv)) << (8 * i);
    *reinterpret_cast<unsigned long long*>(wnS + base) = w0;
    *reinterpret_cast<unsigned long long*>(wnS + base + 128) = w1;
  }
}

// ---- kernel 2: fused fp8 MFMA GEMM + softmax stats (r18 body) ----
// Supply-side occupancy: grid 2048 (PARTS=64); NO VGPR cap (r22's spill trap).
// fp8's natural VGPR (~90) then admits 5 waves/SIMD instead of grid-capped 4.
__launch_bounds__(256, 2)
__global__ void k_main(const unsigned char* __restrict__ xnS,
                       const unsigned char* __restrict__ wnS,
                       const int* __restrict__ label,
                       float* __restrict__ sp, float* __restrict__ vmp,
                       float* __restrict__ vtp) {
  int bid = blockIdx.x;
  int sw = (bid & 7) * 256 + (bid >> 3);  // XCD-contiguous remap (2048 = 8*256)
  int part = sw >> 5;                     // 0..63: column part (96 cols)
  int rowblk = sw & 31;                   // 0..31: 128-row block
  int t = threadIdx.x, w = t >> 6, l = t & 63;
  int lg = l >> 4, lr = l & 15;
  int r0 = rowblk * 128 + w * 32;         // this wave's first row (M=32)

  // A fragments (swizzled fp8, contiguous per wave): 8 bytes per (rt, ks)
  long a[2][8];
#pragma unroll
  for (int rt = 0; rt < 2; ++rt) {
    const unsigned char* ap = xnS + ((r0 >> 4) + rt) * 4096 + lg * 128 + lr * 8;
#pragma unroll
    for (int ks = 0; ks < 8; ++ks)
      a[rt][ks] = *reinterpret_cast<const long*>(ap + ks * 512);
  }
  int lab[8];
#pragma unroll
  for (int rt = 0; rt < 2; ++rt)
#pragma unroll
    for (int j = 0; j < 4; ++j) lab[rt * 4 + j] = label[r0 + rt * 16 + lg * 4 + j];

  float s[8], vm[8], vt[8];
#pragma unroll
  for (int i = 0; i < 8; ++i) { s[i] = 0.f; vm[i] = -2.f; vt[i] = -2.f; }

  // B fragments: chunk c of this part at wnS[part*24576 + c*4096 + ks*512 + l*8]
  const unsigned char* bbase = wnS + (size_t)part * 24576 + l * 8;
  long b[8];
#pragma unroll
  for (int ks = 0; ks < 8; ++ks)
    b[ks] = *reinterpret_cast<const long*>(bbase + ks * 512);

#pragma unroll 2
  for (int c = 0; c < NCH; ++c) {
    long bn[8];
    if (c + 1 < NCH) {  // issue next chunk's loads; hide under MFMA+epilogue
      const unsigned char* bp = bbase + (c + 1) * 4096;
#pragma unroll
      for (int ks = 0; ks < 8; ++ks)
        bn[ks] = *reinterpret_cast<const long*>(bp + ks * 512);
    }
    f32x4 acc0 = {0.f, 0.f, 0.f, 0.f}, acc1 = {0.f, 0.f, 0.f, 0.f};
#pragma unroll
    for (int ks = 0; ks < 8; ++ks) {
      acc0 = __builtin_amdgcn_mfma_f32_16x16x32_fp8_fp8(a[0][ks], b[ks], acc0, 0, 0, 0);
      acc1 = __builtin_amdgcn_mfma_f32_16x16x32_fp8_fp8(a[1][ks], b[ks], acc1, 0, 0, 0);
    }
    int col = part * 96 + c * 16 + lr;
#pragma unroll
    for (int j = 0; j < 4; ++j) {
      float v0 = acc0[j], v1 = acc1[j];
      s[j]     += __expf(__builtin_fmaf(v0, 30.f, -30.f));  // fixed max 30
      s[4 + j] += __expf(__builtin_fmaf(v1, 30.f, -30.f));
      bool i0 = (col == lab[j]), i1 = (col == lab[4 + j]);
      vt[j]     = i0 ? v0 : vt[j];
      vt[4 + j] = i1 ? v1 : vt[4 + j];
      vm[j]     = fmaxf(vm[j],     i0 ? -2.f : v0);
      vm[4 + j] = fmaxf(vm[4 + j], i1 ? -2.f : v1);
    }
#pragma unroll
    for (int ks = 0; ks < 8; ++ks) b[ks] = bn[ks];  // renamed away by unroll
  }

  // reduce across the 16 lanes sharing each output row
#pragma unroll
  for (int i = 0; i < 8; ++i) {
#pragma unroll
    for (int mk = 1; mk < 16; mk <<= 1) {
      s[i] += __shfl_xor(s[i], mk, 64);
      vm[i] = fmaxf(vm[i], __shfl_xor(vm[i], mk, 64));
      vt[i] = fmaxf(vt[i], __shfl_xor(vt[i], mk, 64));
    }
    if (lr == 0) {
      int row = r0 + (i >> 2) * 16 + lg * 4 + (i & 3);
      int idx = row * PARTS + part;      // [row][part] (r11-verified layout)
      sp[idx] = s[i]; vmp[idx] = vm[i]; vtp[idx] = vt[i];
    }
  }
}

// ---- kernel 3 (tail v3, r18-proven): 64 blocks x 64 threads, float4 reads ----
__global__ void k_tail(const float* __restrict__ sp, const float* __restrict__ vmp,
                       const float* __restrict__ vtp, float* __restrict__ accum,
                       float* __restrict__ out) {
  int t = threadIdx.x;            // 64
  int row = blockIdx.x * 64 + t;  // grid 64
  float s = 0.f, vm = -2.f, vt = -2.f;
#pragma unroll
  for (int q = 0; q < PARTS / 4; ++q) {
    float4 aq = reinterpret_cast<const float4*>(sp + row * PARTS)[q];
    float4 mq = reinterpret_cast<const float4*>(vmp + row * PARTS)[q];
    float4 tq = reinterpret_cast<const float4*>(vtp + row * PARTS)[q];
    s += aq.x + aq.y + aq.z + aq.w;
    vm = fmaxf(vm, fmaxf(fmaxf(mq.x, mq.y), fmaxf(mq.z, mq.w)));
    vt = fmaxf(vt, fmaxf(fmaxf(tq.x, tq.y), fmaxf(tq.z, tq.w)));
  }
  float vtc = fminf(fmaxf(vt, -1.f + 1e-7f), 1.f + 1e-7f);
  float sn = sqrtf(fmaxf(1.f - vtc * vtc, 0.f));
  float tg = 30.f * (vtc * COSM - sn * SINM);
  float sadj = s - __expf(30.f * vt - 30.f) + __expf(tg - 30.f);
  float loss = 30.f + logf(sadj) - tg;
  float corr = (tg >= 30.f * vm) ? 1.f : 0.f;
#pragma unroll
  for (int mk = 32; mk >= 1; mk >>= 1) {
    loss += __shfl_xor(loss, mk, 64);
    corr += __shfl_xor(corr, mk, 64);
  }
  if (t == 0) {
    atomicAdd(accum + 0, loss);
    atomicAdd(accum + 1, corr);
    __threadfence();
    unsigned ticket = atomicAdd(reinterpret_cast<unsigned*>(accum) + 2, 1u);
    if (ticket == 63) {  // last block: read via atomic (device-coherent point)
      float L = atomicAdd(accum + 0, 0.0f);
      float Cr = atomicAdd(accum + 1, 0.0f);
      out[0] = L / (float)BB;
      out[1] = Cr * (100.0f / (float)BB);
    }
  }
}

extern "C" void kernel_launch(void* const* d_in, const int* in_sizes, int n_in,
                              void* d_out, int out_size, void* d_ws, size_t ws_size,
                              hipStream_t stream) {
  const float* x = (const float*)d_in[0];
  const float* W = (const float*)d_in[1];
  const int* label = (const int*)d_in[2];
  float* out = (float*)d_out;

  char* ws = (char*)d_ws;
  unsigned char* wnS = (unsigned char*)(ws);                 // 6144*256 = 1,572,864
  unsigned char* xnS = (unsigned char*)(ws + 1572864);       // 4096*256 = 1,048,576
  size_t po = 2621440;
  float* sp  = (float*)(ws + po);                            // 4096*64*4 = 1,048,576
  float* vmp = (float*)(ws + po + 1048576);
  float* vtp = (float*)(ws + po + 2097152);
  float* accum = (float*)(ws + po + 3145728);                // [loss, corr, ticket, pad]

  k_prep<<<1408, 256, 0, stream>>>(x, W, xnS, wnS, (unsigned*)accum);
  k_main<<<2048, 256, 0, stream>>>(xnS, wnS, label, sp, vmp, vtp);
  k_tail<<<BB / 64, 64, 0, stream>>>(sp, vmp, vtp, accum, out);
}

// Round 24
// 35.060 us; speedup vs baseline: 3.2028x; 1.1239x over previous
//
#include <hip/hip_runtime.h>
#include <hip/hip_bf16.h>
#include <hip/hip_fp8.h>

#define BB 4096
#define DD 256
#define CC 5994
#define CPAD 6144
#define PARTS 32
#define NCH 12            // 16-col chunks per part (192 cols/part)
#define COSM 0.9800665778412416f   // cos(0.2)
#define SINM 0.19866933079506122f  // sin(0.2)

typedef __attribute__((ext_vector_type(4))) float f32x4;

__device__ __forceinline__ unsigned char f2fp8(float f) {
  return __hip_fp8_e4m3(f).__x;   // OCP e4m3fn, saturating
}

// ---- kernel 1 (fused prep): blocks 0..1023 xnorm, 1024..1407 wnorm ----
// swizzled fp8 layout (elements == bytes):
//   off = chunk*4096 + ks*512 + lg*128 + lr*8 + h
//   (row|col) = chunk*16 + lr, k = ks*32 + lg*8 + h
__global__ void k_prep(const float* __restrict__ x, const float* __restrict__ W,
                       unsigned char* __restrict__ xnS, unsigned char* __restrict__ wnS,
                       unsigned* __restrict__ accum) {
  int b = blockIdx.x;
  int t = threadIdx.x;
  if (b < 1024) {
    int tgi = t >> 6, l = t & 63;
    int row = b * 4 + tgi;
    float4 v = reinterpret_cast<const float4*>(x + (size_t)row * DD)[l];
    float ss = v.x * v.x + v.y * v.y + v.z * v.z + v.w * v.w;
#pragma unroll
    for (int m = 32; m >= 1; m >>= 1) ss += __shfl_xor(ss, m, 64);
    float inv = 1.0f / fmaxf(sqrtf(ss), 1e-12f);
    unsigned wd = (unsigned)f2fp8(v.x * inv) |
                  ((unsigned)f2fp8(v.y * inv) << 8) |
                  ((unsigned)f2fp8(v.z * inv) << 16) |
                  ((unsigned)f2fp8(v.w * inv) << 24);
    int off = (row >> 4) * 4096 + (l >> 3) * 512 + ((l >> 1) & 3) * 128 + (row & 15) * 8 + (l & 1) * 4;
    *reinterpret_cast<unsigned*>(xnS + off) = wd;
  } else {
    if (b == 1024 && t < 4) accum[t] = 0u;  // loss, corr, ticket, spare
    __shared__ float pp[16][17];
    __shared__ float sinv[16];
    int lr = t & 15, u = t >> 4;
    int bb = b - 1024;
    int chunk = (bb & 7) * 48 + (bb >> 3);  // XCD-locality remap (bijective on [0,384))
    int c = chunk * 16 + lr;
    int D0 = u * 16;
    float v[16];
    float ss = 0.f;
#pragma unroll
    for (int i = 0; i < 16; ++i) {
      float xv = (c < CC) ? W[(size_t)(D0 + i) * CC + c] : 0.f;
      v[i] = xv; ss += xv * xv;
    }
    pp[u][lr] = ss;
    __syncthreads();
    if (t < 16) {
      float tot = 0.f;
#pragma unroll
      for (int g = 0; g < 16; ++g) tot += pp[g][t];
      sinv[t] = (chunk * 16 + t < CC) ? 1.0f / fmaxf(sqrtf(tot), 1e-12f) : 0.f;
    }
    __syncthreads();
    float inv = sinv[lr];
    int base = chunk * 4096 + (u >> 1) * 512 + ((2 * u) & 3) * 128 + lr * 8;
    unsigned long long w0 = 0ull, w1 = 0ull;
#pragma unroll
    for (int i = 0; i < 8; ++i)
      w0 |= ((unsigned long long)f2fp8(v[i] * inv)) << (8 * i);
#pragma unroll
    for (int i = 0; i < 8; ++i)
      w1 |= ((unsigned long long)f2fp8(v[8 + i] * inv)) << (8 * i);
    *reinterpret_cast<unsigned long long*>(wnS + base) = w0;
    *reinterpret_cast<unsigned long long*>(wnS + base + 128) = w1;
  }
}

// ---- kernel 2: fused fp8 MFMA GEMM + softmax stats (r18 body, byte-identical) ----
__launch_bounds__(256, 2)
__global__ void k_main(const unsigned char* __restrict__ xnS,
                       const unsigned char* __restrict__ wnS,
                       const int* __restrict__ label,
                       float* __restrict__ sp, float* __restrict__ vmp,
                       float* __restrict__ vtp) {
  int bid = blockIdx.x;
  int sw = (bid & 7) * 128 + (bid >> 3);  // XCD-contiguous remap (1024 = 8*128)
  int part = sw >> 5;                     // 0..31: column part (192 cols)
  int rowblk = sw & 31;                   // 0..31: 128-row block
  int t = threadIdx.x, w = t >> 6, l = t & 63;
  int lg = l >> 4, lr = l & 15;
  int r0 = rowblk * 128 + w * 32;         // this wave's first row (M=32)

  // A fragments (swizzled fp8, contiguous per wave): 8 bytes per (rt, ks)
  long a[2][8];
#pragma unroll
  for (int rt = 0; rt < 2; ++rt) {
    const unsigned char* ap = xnS + ((r0 >> 4) + rt) * 4096 + lg * 128 + lr * 8;
#pragma unroll
    for (int ks = 0; ks < 8; ++ks)
      a[rt][ks] = *reinterpret_cast<const long*>(ap + ks * 512);
  }
  int lab[8];
#pragma unroll
  for (int rt = 0; rt < 2; ++rt)
#pragma unroll
    for (int j = 0; j < 4; ++j) lab[rt * 4 + j] = label[r0 + rt * 16 + lg * 4 + j];

  float s[8], vm[8], vt[8];
#pragma unroll
  for (int i = 0; i < 8; ++i) { s[i] = 0.f; vm[i] = -2.f; vt[i] = -2.f; }

  // B fragments: chunk c of this part at wnS[part*49152 + c*4096 + ks*512 + l*8]
  const unsigned char* bbase = wnS + (size_t)part * 49152 + l * 8;
  long b[8];
#pragma unroll
  for (int ks = 0; ks < 8; ++ks)
    b[ks] = *reinterpret_cast<const long*>(bbase + ks * 512);

#pragma unroll 2
  for (int c = 0; c < NCH; ++c) {
    long bn[8];
    if (c + 1 < NCH) {  // issue next chunk's loads; hide under MFMA+epilogue
      const unsigned char* bp = bbase + (c + 1) * 4096;
#pragma unroll
      for (int ks = 0; ks < 8; ++ks)
        bn[ks] = *reinterpret_cast<const long*>(bp + ks * 512);
    }
    f32x4 acc0 = {0.f, 0.f, 0.f, 0.f}, acc1 = {0.f, 0.f, 0.f, 0.f};
#pragma unroll
    for (int ks = 0; ks < 8; ++ks) {
      acc0 = __builtin_amdgcn_mfma_f32_16x16x32_fp8_fp8(a[0][ks], b[ks], acc0, 0, 0, 0);
      acc1 = __builtin_amdgcn_mfma_f32_16x16x32_fp8_fp8(a[1][ks], b[ks], acc1, 0, 0, 0);
    }
    int col = part * 192 + c * 16 + lr;
#pragma unroll
    for (int j = 0; j < 4; ++j) {
      float v0 = acc0[j], v1 = acc1[j];
      s[j]     += __expf(__builtin_fmaf(v0, 30.f, -30.f));  // fixed max 30
      s[4 + j] += __expf(__builtin_fmaf(v1, 30.f, -30.f));
      bool i0 = (col == lab[j]), i1 = (col == lab[4 + j]);
      vt[j]     = i0 ? v0 : vt[j];
      vt[4 + j] = i1 ? v1 : vt[4 + j];
      vm[j]     = fmaxf(vm[j],     i0 ? -2.f : v0);
      vm[4 + j] = fmaxf(vm[4 + j], i1 ? -2.f : v1);
    }
#pragma unroll
    for (int ks = 0; ks < 8; ++ks) b[ks] = bn[ks];  // renamed away by unroll
  }

  // reduce across the 16 lanes sharing each output row
#pragma unroll
  for (int i = 0; i < 8; ++i) {
#pragma unroll
    for (int mk = 1; mk < 16; mk <<= 1) {
      s[i] += __shfl_xor(s[i], mk, 64);
      vm[i] = fmaxf(vm[i], __shfl_xor(vm[i], mk, 64));
      vt[i] = fmaxf(vt[i], __shfl_xor(vt[i], mk, 64));
    }
    if (lr == 0) {
      int row = r0 + (i >> 2) * 16 + lg * 4 + (i & 3);
      int idx = row * PARTS + part;      // [row][part] (r11-verified layout)
      sp[idx] = s[i]; vmp[idx] = vm[i]; vtp[idx] = vt[i];
    }
  }
}

// ---- kernel 3 (tail v3, r18-proven): 64 blocks x 64 threads, float4 reads ----
__global__ void k_tail(const float* __restrict__ sp, const float* __restrict__ vmp,
                       const float* __restrict__ vtp, float* __restrict__ accum,
                       float* __restrict__ out) {
  int t = threadIdx.x;            // 64
  int row = blockIdx.x * 64 + t;  // grid 64
  float s = 0.f, vm = -2.f, vt = -2.f;
#pragma unroll
  for (int q = 0; q < 8; ++q) {
    float4 aq = reinterpret_cast<const float4*>(sp + row * PARTS)[q];
    float4 mq = reinterpret_cast<const float4*>(vmp + row * PARTS)[q];
    float4 tq = reinterpret_cast<const float4*>(vtp + row * PARTS)[q];
    s += aq.x + aq.y + aq.z + aq.w;
    vm = fmaxf(vm, fmaxf(fmaxf(mq.x, mq.y), fmaxf(mq.z, mq.w)));
    vt = fmaxf(vt, fmaxf(fmaxf(tq.x, tq.y), fmaxf(tq.z, tq.w)));
  }
  float vtc = fminf(fmaxf(vt, -1.f + 1e-7f), 1.f + 1e-7f);
  float sn = sqrtf(fmaxf(1.f - vtc * vtc, 0.f));
  float tg = 30.f * (vtc * COSM - sn * SINM);
  float sadj = s - __expf(30.f * vt - 30.f) + __expf(tg - 30.f);
  float loss = 30.f + logf(sadj) - tg;
  float corr = (tg >= 30.f * vm) ? 1.f : 0.f;
#pragma unroll
  for (int mk = 32; mk >= 1; mk >>= 1) {
    loss += __shfl_xor(loss, mk, 64);
    corr += __shfl_xor(corr, mk, 64);
  }
  if (t == 0) {
    atomicAdd(accum + 0, loss);
    atomicAdd(accum + 1, corr);
    __threadfence();
    unsigned ticket = atomicAdd(reinterpret_cast<unsigned*>(accum) + 2, 1u);
    if (ticket == 63) {  // last block: read via atomic (device-coherent point)
      float L = atomicAdd(accum + 0, 0.0f);
      float Cr = atomicAdd(accum + 1, 0.0f);
      out[0] = L / (float)BB;
      out[1] = Cr * (100.0f / (float)BB);
    }
  }
}

extern "C" void kernel_launch(void* const* d_in, const int* in_sizes, int n_in,
                              void* d_out, int out_size, void* d_ws, size_t ws_size,
                              hipStream_t stream) {
  const float* x = (const float*)d_in[0];
  const float* W = (const float*)d_in[1];
  const int* label = (const int*)d_in[2];
  float* out = (float*)d_out;

  char* ws = (char*)d_ws;
  unsigned char* wnS = (unsigned char*)(ws);                 // 6144*256 = 1,572,864
  unsigned char* xnS = (unsigned char*)(ws + 1572864);       // 4096*256 = 1,048,576
  size_t po = 2621440;
  float* sp  = (float*)(ws + po);                            // 4096*32*4 = 524,288
  float* vmp = (float*)(ws + po + 524288);
  float* vtp = (float*)(ws + po + 1048576);
  float* accum = (float*)(ws + po + 1572864);                // [loss, corr, ticket, pad]

  k_prep<<<1408, 256, 0, stream>>>(x, W, xnS, wnS, (unsigned*)accum);
  k_main<<<1024, 256, 0, stream>>>(xnS, wnS, label, sp, vmp, vtp);
  k_tail<<<BB / 64, 64, 0, stream>>>(sp, vmp, vtp, accum, out);
}